// Round 6
// baseline (5562.123 us; speedup 1.0000x reference)
//
#include <hip/hip_runtime.h>

// ---------------------------------------------------------------------------
// GAT 2-layer forward, workspace-adaptive head grouping.
// Layer1: in=128, H=8, F=32.  Layer2: in=32, H=8, F=16.  N=1e5, E=1.6e6.
// Heads processed in groups of HG (8/4/2/1 chosen so ws fits ws_size).
// Softmax without max-subtraction (values O(1); exp can't overflow in f32).
// Head-mean fused into aggregation (0.125 scale at atomicAdd).
// Layer2 aggregates directly into d_out; bias added in-place afterwards.
// (Resubmission: rounds 2-5 failed on harness-side disk space before the
//  kernel was ever compiled/launched.)
// ---------------------------------------------------------------------------

__device__ __forceinline__ float lrelu_exp(float v) {
    v = v > 0.f ? v : 0.2f * v;
    return __expf(v);
}

__global__ __launch_bounds__(256) void k_zero(float* __restrict__ p, int n) {
    int i = blockIdx.x * 256 + threadIdx.x;
    const int stride = gridDim.x * 256;
    for (; i < n; i += stride) p[i] = 0.f;
}

// Tile-GEMM: x[N,IN] @ W[:, c0:c0+C] -> h[N,C].  W is [IN, OW] row-major.
// 32 nodes per block, 256 threads.
template <int IN, int C, int OW>
__global__ __launch_bounds__(256) void k_gemm(const float* __restrict__ x,
                                              const float* __restrict__ W,
                                              float* __restrict__ h, int N, int c0) {
    __shared__ float xs[32 * IN];
    const int t  = threadIdx.x;
    const int n0 = blockIdx.x * 32;
    const float4* src4 = (const float4*)(x + (size_t)n0 * IN);
    float4* xs4 = (float4*)xs;
    constexpr int NV = 32 * IN / 4;
#pragma unroll
    for (int idx = t; idx < NV; idx += 256) {
        const int row = idx / (IN / 4);
        xs4[idx] = (n0 + row < N) ? src4[idx] : make_float4(0.f, 0.f, 0.f, 0.f);
    }
    __syncthreads();

    const int c  = t % C;
    const int r0 = t / C;
    constexpr int RSTEP = 256 / C;
    constexpr int RPT   = 32 / RSTEP;
    float acc[RPT];
#pragma unroll
    for (int i = 0; i < RPT; ++i) acc[i] = 0.f;
    const float* Wc = W + c0 + c;
#pragma unroll 1
    for (int k = 0; k < IN; k += 4) {
        const float w0 = Wc[(k + 0) * OW];
        const float w1 = Wc[(k + 1) * OW];
        const float w2 = Wc[(k + 2) * OW];
        const float w3 = Wc[(k + 3) * OW];
#pragma unroll
        for (int i = 0; i < RPT; ++i) {
            const int r = r0 + i * RSTEP;
            const float4 xv = *(const float4*)&xs[r * IN + k];
            acc[i] = fmaf(xv.x, w0, fmaf(xv.y, w1, fmaf(xv.z, w2, fmaf(xv.w, w3, acc[i]))));
        }
    }
#pragma unroll
    for (int i = 0; i < RPT; ++i) {
        const int r = r0 + i * RSTEP;
        if (n0 + r < N) h[(size_t)(n0 + r) * C + c] = acc[i];
    }
}

// Attention dots for one head group: h is [N, HG, F] flattened; i = n*HG + hl.
template <int F, int HG>
__global__ __launch_bounds__(256) void k_dots(const float* __restrict__ h,
                                              const float* __restrict__ atts,
                                              const float* __restrict__ attd,
                                              float* __restrict__ as_,
                                              float* __restrict__ ad_, int NH, int g) {
    const int i = blockIdx.x * 256 + threadIdx.x;
    if (i >= NH) return;
    const int hg = g * HG + (i & (HG - 1));
    const float4* hv = (const float4*)(h + (size_t)i * F);
    const float4* sv = (const float4*)(atts + hg * F);
    const float4* dv = (const float4*)(attd + hg * F);
    float s = 0.f, d = 0.f;
#pragma unroll
    for (int q = 0; q < F / 4; ++q) {
        const float4 xv = hv[q], a = sv[q], b = dv[q];
        s += xv.x * a.x + xv.y * a.y + xv.z * a.z + xv.w * a.w;
        d += xv.x * b.x + xv.y * b.y + xv.z * b.z + xv.w * b.w;
    }
    as_[i] = s;
    ad_[i] = d;
}

// Edge pass 1: softmax denominators per (dst, head-in-group).
template <int HG>
__global__ __launch_bounds__(256) void k_edge_sum(const int* __restrict__ ei,
                                                  const float* __restrict__ as_,
                                                  const float* __restrict__ ad_,
                                                  float* __restrict__ ssum, int E) {
    const int e = blockIdx.x * 256 + threadIdx.x;
    if (e >= E) return;
    const int src = ei[e];
    const int dst = ei[E + e];
    const float* sp = as_ + (size_t)src * HG;
    const float* dp = ad_ + (size_t)dst * HG;
    float* sb = ssum + (size_t)dst * HG;
#pragma unroll
    for (int hh = 0; hh < HG; ++hh) atomicAdd(sb + hh, lrelu_exp(sp[hh] + dp[hh]));
}

// Edge pass 2: acc[dst, f] += (1/8) * sum_{h in group} alpha_eh * h[src, h, f]
template <int F, int HG>
__global__ __launch_bounds__(256) void k_agg(const int* __restrict__ ei,
                                             const float* __restrict__ as_,
                                             const float* __restrict__ ad_,
                                             const float* __restrict__ ssum,
                                             const float* __restrict__ h,
                                             float* __restrict__ acc, int E) {
    const int e = blockIdx.x * 256 + threadIdx.x;
    if (e >= E) return;
    const int src = ei[e];
    const int dst = ei[E + e];
    const float* sp = as_ + (size_t)src * HG;
    const float* dp = ad_ + (size_t)dst * HG;
    const float* qp = ssum + (size_t)dst * HG;
    float al[HG];
#pragma unroll
    for (int hh = 0; hh < HG; ++hh)
        al[hh] = lrelu_exp(sp[hh] + dp[hh]) / (qp[hh] + 1e-16f);

    const float* hr = h + (size_t)src * HG * F;
    float4 v[F / 4];
#pragma unroll
    for (int q = 0; q < F / 4; ++q) v[q] = make_float4(0.f, 0.f, 0.f, 0.f);
#pragma unroll
    for (int hh = 0; hh < HG; ++hh) {
        const float a = al[hh];
#pragma unroll
        for (int q = 0; q < F / 4; ++q) {
            const float4 xv = *(const float4*)(hr + hh * F + q * 4);
            v[q].x = fmaf(a, xv.x, v[q].x);
            v[q].y = fmaf(a, xv.y, v[q].y);
            v[q].z = fmaf(a, xv.z, v[q].z);
            v[q].w = fmaf(a, xv.w, v[q].w);
        }
    }
    float* ab = acc + (size_t)dst * F;
#pragma unroll
    for (int q = 0; q < F / 4; ++q) {
        atomicAdd(ab + q * 4 + 0, v[q].x * 0.125f);
        atomicAdd(ab + q * 4 + 1, v[q].y * 0.125f);
        atomicAdd(ab + q * 4 + 2, v[q].z * 0.125f);
        atomicAdd(ab + q * 4 + 3, v[q].w * 0.125f);
    }
}

__global__ __launch_bounds__(256) void k_relu_bias(float* __restrict__ a,
                                                   const float* __restrict__ b, int total) {
    const int i = blockIdx.x * 256 + threadIdx.x;
    if (i < total) {
        const float v = a[i] + b[i & 31];
        a[i] = v > 0.f ? v : 0.f;
    }
}

__global__ __launch_bounds__(256) void k_bias_inplace(float* __restrict__ a,
                                                      const float* __restrict__ b, int total) {
    const int i = blockIdx.x * 256 + threadIdx.x;
    if (i < total) a[i] += b[i & 15];
}

template <int HG>
static void run_pipeline(const float* x, const int* ei,
                         const float* W1, const float* as1, const float* ad1, const float* b1,
                         const float* W2, const float* as2, const float* ad2, const float* b2,
                         float* out, int N, int E, char* ws, hipStream_t stream) {
    float* hbuf = (float*)ws;                         // [N, HG*32] (layer2 uses [N, HG*16])
    float* a_s  = hbuf + (size_t)N * HG * 32;
    float* a_d  = a_s + (size_t)N * HG;
    float* ssum = a_d + (size_t)N * HG;
    float* acc1 = ssum + (size_t)N * HG;              // [N, 32]

    const int nb_nodes = (N + 31) / 32;
    const int nb_edges = (E + 255) / 256;
    const int nb_pairs = (N * HG + 255) / 256;
    constexpr int G = 8 / HG;

    k_zero<<<512, 256, 0, stream>>>(acc1, N * 32);
    k_zero<<<512, 256, 0, stream>>>(out, N * 16);

    for (int g = 0; g < G; ++g) {
        k_gemm<128, HG * 32, 256><<<nb_nodes, 256, 0, stream>>>(x, W1, hbuf, N, g * HG * 32);
        k_dots<32, HG><<<nb_pairs, 256, 0, stream>>>(hbuf, as1, ad1, a_s, a_d, N * HG, g);
        k_zero<<<512, 256, 0, stream>>>(ssum, N * HG);
        k_edge_sum<HG><<<nb_edges, 256, 0, stream>>>(ei, a_s, a_d, ssum, E);
        k_agg<32, HG><<<nb_edges, 256, 0, stream>>>(ei, a_s, a_d, ssum, hbuf, acc1, E);
    }
    k_relu_bias<<<(N * 32 + 255) / 256, 256, 0, stream>>>(acc1, b1, N * 32);

    for (int g = 0; g < G; ++g) {
        k_gemm<32, HG * 16, 128><<<nb_nodes, 256, 0, stream>>>(acc1, W2, hbuf, N, g * HG * 16);
        k_dots<16, HG><<<nb_pairs, 256, 0, stream>>>(hbuf, as2, ad2, a_s, a_d, N * HG, g);
        k_zero<<<512, 256, 0, stream>>>(ssum, N * HG);
        k_edge_sum<HG><<<nb_edges, 256, 0, stream>>>(ei, a_s, a_d, ssum, E);
        k_agg<16, HG><<<nb_edges, 256, 0, stream>>>(ei, a_s, a_d, ssum, hbuf, out, E);
    }
    k_bias_inplace<<<(N * 16 + 255) / 256, 256, 0, stream>>>(out, b2, N * 16);
}

extern "C" void kernel_launch(void* const* d_in, const int* in_sizes, int n_in,
                              void* d_out, int out_size, void* d_ws, size_t ws_size,
                              hipStream_t stream) {
    const float* x   = (const float*)d_in[0];
    const int*   ei  = (const int*)d_in[1];
    const float* W1  = (const float*)d_in[2];
    const float* as1 = (const float*)d_in[3];
    const float* ad1 = (const float*)d_in[4];
    const float* b1  = (const float*)d_in[5];
    const float* W2  = (const float*)d_in[6];
    const float* as2 = (const float*)d_in[7];
    const float* ad2 = (const float*)d_in[8];
    const float* b2  = (const float*)d_in[9];
    float* out = (float*)d_out;

    const int N = in_sizes[0] / 128;
    const int E = in_sizes[1] / 2;

    // ws bytes needed for head-group size hg: hbuf + a_s + a_d + ssum + acc1
    auto need = [&](int hg) {
        return (size_t)4 * (size_t)N * ((size_t)hg * 32 + 3 * (size_t)hg + 32);
    };
    char* ws = (char*)d_ws;
    if (ws_size >= need(8)) {
        run_pipeline<8>(x, ei, W1, as1, ad1, b1, W2, as2, ad2, b2, out, N, E, ws, stream);
    } else if (ws_size >= need(4)) {
        run_pipeline<4>(x, ei, W1, as1, ad1, b1, W2, as2, ad2, b2, out, N, E, ws, stream);
    } else if (ws_size >= need(2)) {
        run_pipeline<2>(x, ei, W1, as1, ad1, b1, W2, as2, ad2, b2, out, N, E, ws, stream);
    } else {
        run_pipeline<1>(x, ei, W1, as1, ad1, b1, W2, as2, ad2, b2, out, N, E, ws, stream);
    }
}

// Round 7
// 902.346 us; speedup vs baseline: 6.1641x; 6.1641x over previous
//
#include <hip/hip_runtime.h>

// ---------------------------------------------------------------------------
// GAT 2-layer forward, CSR owner-computes aggregation (no float atomics).
// Layer1: in=128, H=8, F=32.  Layer2: in=32, H=8, F=16.  N=1e5, E=1.6e6.
// Round-6 profile: 51.2M device-scope f32 atomicAdds = 1.64 GB of 32B HBM
// transactions = 2.7ms (VALUBusy 0.7%). Fix: build CSR by dst on device
// (hist -> scan -> scatter), then thread=(node,f) owns its output: pass1
// computes softmax denom, pass2 weighted gather, plain stores. k_edge_sum
// deleted. Softmax without max-subtraction (O(1) logits, exact in f32).
// Head-mean fused (0.125). Heads grouped by HG=8/4/2/1 to fit ws_size.
// ---------------------------------------------------------------------------

__device__ __forceinline__ float lrelu_exp(float v) {
    v = v > 0.f ? v : 0.2f * v;
    return __expf(v);
}

__global__ __launch_bounds__(256) void k_zero(float* __restrict__ p, int n) {
    int i = blockIdx.x * 256 + threadIdx.x;
    const int stride = gridDim.x * 256;
    for (; i < n; i += stride) p[i] = 0.f;
}

__global__ __launch_bounds__(256) void k_zero_int(int* __restrict__ p, int n) {
    int i = blockIdx.x * 256 + threadIdx.x;
    const int stride = gridDim.x * 256;
    for (; i < n; i += stride) p[i] = 0;
}

// ---------------- CSR build ----------------
__global__ __launch_bounds__(256) void k_hist(const int* __restrict__ ei,
                                              int* __restrict__ deg, int E) {
    const int e = blockIdx.x * 256 + threadIdx.x;
    if (e < E) atomicAdd(&deg[ei[E + e]], 1);
}

// Per-block exclusive scan of deg -> rowptr (local), block totals -> bsum.
__global__ __launch_bounds__(256) void k_scan_block(const int* __restrict__ deg,
                                                    int* __restrict__ rowptr,
                                                    int* __restrict__ bsum, int N) {
    __shared__ int s[256];
    const int t = threadIdx.x;
    const int i = blockIdx.x * 256 + t;
    const int v = (i < N) ? deg[i] : 0;
    s[t] = v;
    __syncthreads();
    for (int off = 1; off < 256; off <<= 1) {
        const int tv = (t >= off) ? s[t - off] : 0;
        __syncthreads();
        s[t] += tv;
        __syncthreads();
    }
    if (i < N) rowptr[i] = s[t] - v;           // exclusive within block
    if (t == 255) bsum[blockIdx.x] = s[255];   // block total
}

// Single-block exclusive scan of block sums (NB <= 1024).
__global__ __launch_bounds__(1024) void k_scan_sums(int* __restrict__ bsum, int NB) {
    __shared__ int s[1024];
    const int t = threadIdx.x;
    const int v = (t < NB) ? bsum[t] : 0;
    s[t] = v;
    __syncthreads();
    for (int off = 1; off < 1024; off <<= 1) {
        const int tv = (t >= off) ? s[t - off] : 0;
        __syncthreads();
        s[t] += tv;
        __syncthreads();
    }
    if (t < NB) bsum[t] = s[t] - v;            // exclusive
}

// Add block offsets; copy to cursor; set rowptr[N] = E.
__global__ __launch_bounds__(256) void k_scan_add(int* __restrict__ rowptr,
                                                  const int* __restrict__ bsum,
                                                  int* __restrict__ cursor, int N, int E) {
    const int i = blockIdx.x * 256 + threadIdx.x;
    if (i < N) {
        const int r = rowptr[i] + bsum[blockIdx.x];
        rowptr[i] = r;
        cursor[i] = r;
    }
    if (i == 0) rowptr[N] = E;
}

__global__ __launch_bounds__(256) void k_scatter(const int* __restrict__ ei,
                                                 int* __restrict__ cursor,
                                                 int* __restrict__ esrc, int E) {
    const int e = blockIdx.x * 256 + threadIdx.x;
    if (e >= E) return;
    const int src = ei[e];
    const int dst = ei[E + e];
    const int pos = atomicAdd(&cursor[dst], 1);
    esrc[pos] = src;
}

// ---------------- dense phase ----------------
// Tile-GEMM: x[N,IN] @ W[:, c0:c0+C] -> h[N,C].  W is [IN, OW] row-major.
template <int IN, int C, int OW>
__global__ __launch_bounds__(256) void k_gemm(const float* __restrict__ x,
                                              const float* __restrict__ W,
                                              float* __restrict__ h, int N, int c0) {
    __shared__ float xs[32 * IN];
    const int t  = threadIdx.x;
    const int n0 = blockIdx.x * 32;
    const float4* src4 = (const float4*)(x + (size_t)n0 * IN);
    float4* xs4 = (float4*)xs;
    constexpr int NV = 32 * IN / 4;
#pragma unroll
    for (int idx = t; idx < NV; idx += 256) {
        const int row = idx / (IN / 4);
        xs4[idx] = (n0 + row < N) ? src4[idx] : make_float4(0.f, 0.f, 0.f, 0.f);
    }
    __syncthreads();

    const int c  = t % C;
    const int r0 = t / C;
    constexpr int RSTEP = 256 / C;
    constexpr int RPT   = 32 / RSTEP;
    float acc[RPT];
#pragma unroll
    for (int i = 0; i < RPT; ++i) acc[i] = 0.f;
    const float* Wc = W + c0 + c;
#pragma unroll 1
    for (int k = 0; k < IN; k += 4) {
        const float w0 = Wc[(k + 0) * OW];
        const float w1 = Wc[(k + 1) * OW];
        const float w2 = Wc[(k + 2) * OW];
        const float w3 = Wc[(k + 3) * OW];
#pragma unroll
        for (int i = 0; i < RPT; ++i) {
            const int r = r0 + i * RSTEP;
            const float4 xv = *(const float4*)&xs[r * IN + k];
            acc[i] = fmaf(xv.x, w0, fmaf(xv.y, w1, fmaf(xv.z, w2, fmaf(xv.w, w3, acc[i]))));
        }
    }
#pragma unroll
    for (int i = 0; i < RPT; ++i) {
        const int r = r0 + i * RSTEP;
        if (n0 + r < N) h[(size_t)(n0 + r) * C + c] = acc[i];
    }
}

// Attention dots: h is [N, HG, F]; writes a_s/a_d at [n, hb+hl] in [N,8] layout.
template <int F, int HG>
__global__ __launch_bounds__(256) void k_dots(const float* __restrict__ h,
                                              const float* __restrict__ atts,
                                              const float* __restrict__ attd,
                                              float* __restrict__ as_,
                                              float* __restrict__ ad_, int N, int hb) {
    const int i = blockIdx.x * 256 + threadIdx.x;
    if (i >= N * HG) return;
    const int n  = i / HG;
    const int hl = i % HG;
    const int hg = hb + hl;
    const float4* hv = (const float4*)(h + (size_t)i * F);
    const float4* sv = (const float4*)(atts + hg * F);
    const float4* dv = (const float4*)(attd + hg * F);
    float s = 0.f, d = 0.f;
#pragma unroll
    for (int q = 0; q < F / 4; ++q) {
        const float4 xv = hv[q], a = sv[q], b = dv[q];
        s += xv.x * a.x + xv.y * a.y + xv.z * a.z + xv.w * a.w;
        d += xv.x * b.x + xv.y * b.y + xv.z * b.z + xv.w * b.w;
    }
    as_[(size_t)n * 8 + hg] = s;
    ad_[(size_t)n * 8 + hg] = d;
}

// Owner-computes aggregation. thread = (node, f). h is [N, HG, F] (this
// group's heads). acc[n*F+f] += 0.125 * sum_h sum_e alpha * h[src,h,f].
template <int F, int HG>
__global__ __launch_bounds__(256) void k_csr_agg(const int* __restrict__ rowptr,
                                                 const int* __restrict__ esrc,
                                                 const float* __restrict__ as_,
                                                 const float* __restrict__ ad_,
                                                 const float* __restrict__ h,
                                                 float* __restrict__ acc,
                                                 int N, int hb) {
    constexpr int NPB = 256 / F;
    const int n = blockIdx.x * NPB + threadIdx.x / F;
    const int f = threadIdx.x % F;
    if (n >= N) return;
    const int r0 = rowptr[n];
    const int r1 = rowptr[n + 1];

    float ad[HG], denom[HG];
#pragma unroll
    for (int k = 0; k < HG; ++k) {
        ad[k] = ad_[(size_t)n * 8 + hb + k];
        denom[k] = 0.f;
    }
    // pass 1: softmax denominators (all F lanes redundantly; VALU is idle)
    for (int e = r0; e < r1; ++e) {
        const int src = esrc[e];
        const float* sp = as_ + (size_t)src * 8 + hb;
#pragma unroll
        for (int k = 0; k < HG; ++k) denom[k] += lrelu_exp(sp[k] + ad[k]);
    }
#pragma unroll
    for (int k = 0; k < HG; ++k) denom[k] = 1.f / (denom[k] + 1e-16f);

    // pass 2: weighted gather
    float a = 0.f;
    for (int e = r0; e < r1; ++e) {
        const int src = esrc[e];
        const float* sp = as_ + (size_t)src * 8 + hb;
        const float* hr = h + (size_t)src * (HG * F) + f;
#pragma unroll
        for (int k = 0; k < HG; ++k) {
            const float al = lrelu_exp(sp[k] + ad[k]) * denom[k];
            a = fmaf(al, hr[k * F], a);
        }
    }
    acc[(size_t)n * F + f] += 0.125f * a;
}

__global__ __launch_bounds__(256) void k_relu_bias(float* __restrict__ a,
                                                   const float* __restrict__ b, int total) {
    const int i = blockIdx.x * 256 + threadIdx.x;
    if (i < total) {
        const float v = a[i] + b[i & 31];
        a[i] = v > 0.f ? v : 0.f;
    }
}

__global__ __launch_bounds__(256) void k_bias_inplace(float* __restrict__ a,
                                                      const float* __restrict__ b, int total) {
    const int i = blockIdx.x * 256 + threadIdx.x;
    if (i < total) a[i] += b[i & 15];
}

template <int HG>
static void run_pipeline(const float* x, const int* ei,
                         const float* W1, const float* as1, const float* ad1, const float* b1,
                         const float* W2, const float* as2, const float* ad2, const float* b2,
                         float* out, int N, int E, char* ws, hipStream_t stream) {
    // ws layout
    float* hbuf  = (float*)ws;                          // [N, HG*32] (layer2: [N, HG*16])
    float* a_s   = hbuf + (size_t)N * HG * 32;          // [N, 8]
    float* a_d   = a_s + (size_t)N * 8;                 // [N, 8]
    float* acc1  = a_d + (size_t)N * 8;                 // [N, 32]
    int* rowptr  = (int*)(acc1 + (size_t)N * 32);       // [N+1]
    int* cursor  = rowptr + (N + 1);                    // [N]
    int* deg     = cursor + N;                          // [N]
    int* bsum    = deg + N;                             // [1024]
    int* esrc    = bsum + 1024;                         // [E]

    const int NBn = (N + 255) / 256;       // node-parallel blocks / scan blocks
    const int NBe = (E + 255) / 256;       // edge-parallel blocks
    constexpr int G = 8 / HG;

    // ---- CSR build (shared by both layers) ----
    k_zero_int<<<512, 256, 0, stream>>>(deg, N);
    k_hist<<<NBe, 256, 0, stream>>>(ei, deg, E);
    k_scan_block<<<NBn, 256, 0, stream>>>(deg, rowptr, bsum, N);
    k_scan_sums<<<1, 1024, 0, stream>>>(bsum, NBn);
    k_scan_add<<<NBn, 256, 0, stream>>>(rowptr, bsum, cursor, N, E);
    k_scatter<<<NBe, 256, 0, stream>>>(ei, cursor, esrc, E);

    k_zero<<<512, 256, 0, stream>>>(acc1, N * 32);
    k_zero<<<512, 256, 0, stream>>>(out, N * 16);

    // ---- layer 1 ----
    for (int g = 0; g < G; ++g) {
        k_gemm<128, HG * 32, 256><<<NBn * 8, 256, 0, stream>>>(x, W1, hbuf, N, g * HG * 32);
        k_dots<32, HG><<<(N * HG + 255) / 256, 256, 0, stream>>>(hbuf, as1, ad1, a_s, a_d, N, g * HG);
        k_csr_agg<32, HG><<<(N + 7) / 8, 256, 0, stream>>>(rowptr, esrc, a_s, a_d, hbuf, acc1, N, g * HG);
    }
    k_relu_bias<<<(N * 32 + 255) / 256, 256, 0, stream>>>(acc1, b1, N * 32);

    // ---- layer 2 ----
    for (int g = 0; g < G; ++g) {
        k_gemm<32, HG * 16, 128><<<NBn * 8, 256, 0, stream>>>(acc1, W2, hbuf, N, g * HG * 16);
        k_dots<16, HG><<<(N * HG + 255) / 256, 256, 0, stream>>>(hbuf, as2, ad2, a_s, a_d, N, g * HG);
        k_csr_agg<16, HG><<<(N + 15) / 16, 256, 0, stream>>>(rowptr, esrc, a_s, a_d, hbuf, out, N, g * HG);
    }
    k_bias_inplace<<<(N * 16 + 255) / 256, 256, 0, stream>>>(out, b2, N * 16);
}

extern "C" void kernel_launch(void* const* d_in, const int* in_sizes, int n_in,
                              void* d_out, int out_size, void* d_ws, size_t ws_size,
                              hipStream_t stream) {
    const float* x   = (const float*)d_in[0];
    const int*   ei  = (const int*)d_in[1];
    const float* W1  = (const float*)d_in[2];
    const float* as1 = (const float*)d_in[3];
    const float* ad1 = (const float*)d_in[4];
    const float* b1  = (const float*)d_in[5];
    const float* W2  = (const float*)d_in[6];
    const float* as2 = (const float*)d_in[7];
    const float* ad2 = (const float*)d_in[8];
    const float* b2  = (const float*)d_in[9];
    float* out = (float*)d_out;

    const int N = in_sizes[0] / 128;
    const int E = in_sizes[1] / 2;

    // bytes for head-group size hg:
    // hbuf(N*hg*32) + a_s(N*8) + a_d(N*8) + acc1(N*32)  floats
    // + rowptr(N+1) + cursor(N) + deg(N) + bsum(1024) + esrc(E)  ints
    auto need = [&](int hg) {
        return (size_t)4 * ((size_t)N * ((size_t)hg * 32 + 48) +
                            (size_t)3 * N + 1 + 1024 + (size_t)E);
    };
    char* ws = (char*)d_ws;
    if (ws_size >= need(8)) {
        run_pipeline<8>(x, ei, W1, as1, ad1, b1, W2, as2, ad2, b2, out, N, E, ws, stream);
    } else if (ws_size >= need(4)) {
        run_pipeline<4>(x, ei, W1, as1, ad1, b1, W2, as2, ad2, b2, out, N, E, ws, stream);
    } else if (ws_size >= need(2)) {
        run_pipeline<2>(x, ei, W1, as1, ad1, b1, W2, as2, ad2, b2, out, N, E, ws, stream);
    } else {
        run_pipeline<1>(x, ei, W1, as1, ad1, b1, W2, as2, ad2, b2, out, N, E, ws, stream);
    }
}

// Round 8
// 708.085 us; speedup vs baseline: 7.8552x; 1.2743x over previous
//
#include <hip/hip_runtime.h>
#include <hip/hip_fp16.h>

// ---------------------------------------------------------------------------
// GAT 2-layer forward. CSR owner-computes aggregation, fp16 feature gather.
// Layer1: in=128, H=8, F=32.  Layer2: in=32, H=8, F=16.  N=1e5, E=1.6e6.
// Round-7 profile: k_agg = 305us, FETCH 942MB, VALU 77% (mixed-bound:
// 1KB/edge f32 gather + 819M redundant exps). This round:
//  - h stored fp16 in [N, F, H] layout -> per-edge gather is a contiguous
//    512B row (half8 per lane), half the bytes.
//  - softmax denominators moved to k_denom (thread=(node,head), E*8 exps
//    total); agg is single-pass with alpha = exp * rinv.
//  - HG=8 path: agg WRITES output (no +=): layer1 fuses relu+bias, layer2
//    fuses bias and writes d_out directly. No zero-fills needed.
// Softmax without max-subtraction (O(1) logits; exact in f32; validated
// rounds 6-7 at absmax 2.4e-4).
// ---------------------------------------------------------------------------

__device__ __forceinline__ float lrelu_exp(float v) {
    v = v > 0.f ? v : 0.2f * v;
    return __expf(v);
}

__global__ __launch_bounds__(256) void k_zero(float* __restrict__ p, int n) {
    int i = blockIdx.x * 256 + threadIdx.x;
    const int stride = gridDim.x * 256;
    for (; i < n; i += stride) p[i] = 0.f;
}

__global__ __launch_bounds__(256) void k_zero_int(int* __restrict__ p, int n) {
    int i = blockIdx.x * 256 + threadIdx.x;
    const int stride = gridDim.x * 256;
    for (; i < n; i += stride) p[i] = 0;
}

// ---------------- CSR build (unchanged from round 7) ----------------
__global__ __launch_bounds__(256) void k_hist(const int* __restrict__ ei,
                                              int* __restrict__ deg, int E) {
    const int e = blockIdx.x * 256 + threadIdx.x;
    if (e < E) atomicAdd(&deg[ei[E + e]], 1);
}

__global__ __launch_bounds__(256) void k_scan_block(const int* __restrict__ deg,
                                                    int* __restrict__ rowptr,
                                                    int* __restrict__ bsum, int N) {
    __shared__ int s[256];
    const int t = threadIdx.x;
    const int i = blockIdx.x * 256 + t;
    const int v = (i < N) ? deg[i] : 0;
    s[t] = v;
    __syncthreads();
    for (int off = 1; off < 256; off <<= 1) {
        const int tv = (t >= off) ? s[t - off] : 0;
        __syncthreads();
        s[t] += tv;
        __syncthreads();
    }
    if (i < N) rowptr[i] = s[t] - v;
    if (t == 255) bsum[blockIdx.x] = s[255];
}

__global__ __launch_bounds__(1024) void k_scan_sums(int* __restrict__ bsum, int NB) {
    __shared__ int s[1024];
    const int t = threadIdx.x;
    const int v = (t < NB) ? bsum[t] : 0;
    s[t] = v;
    __syncthreads();
    for (int off = 1; off < 1024; off <<= 1) {
        const int tv = (t >= off) ? s[t - off] : 0;
        __syncthreads();
        s[t] += tv;
        __syncthreads();
    }
    if (t < NB) bsum[t] = s[t] - v;
}

__global__ __launch_bounds__(256) void k_scan_add(int* __restrict__ rowptr,
                                                  const int* __restrict__ bsum,
                                                  int* __restrict__ cursor, int N, int E) {
    const int i = blockIdx.x * 256 + threadIdx.x;
    if (i < N) {
        const int r = rowptr[i] + bsum[blockIdx.x];
        rowptr[i] = r;
        cursor[i] = r;
    }
    if (i == 0) rowptr[N] = E;
}

__global__ __launch_bounds__(256) void k_scatter(const int* __restrict__ ei,
                                                 int* __restrict__ cursor,
                                                 int* __restrict__ esrc, int E) {
    const int e = blockIdx.x * 256 + threadIdx.x;
    if (e >= E) return;
    const int src = ei[e];
    const int dst = ei[E + e];
    const int pos = atomicAdd(&cursor[dst], 1);
    esrc[pos] = src;
}

// ---------------- dense phase ----------------
// GEMM: x[N,IN] @ W[:, cols of group] -> h fp16 [N, F, HG] (per-group).
// Thread t owns output slot idx=t%C where f=idx/HG, head_l=idx%HG;
// W column = c0 + head_l*F + f.  Output stores are contiguous in idx.
template <int IN, int C, int OW, int F>
__global__ __launch_bounds__(256) void k_gemm_h(const float* __restrict__ x,
                                                const float* __restrict__ W,
                                                __half* __restrict__ h, int N, int c0) {
    constexpr int HG = C / F;
    __shared__ float xs[32 * IN];
    const int t  = threadIdx.x;
    const int n0 = blockIdx.x * 32;
    const float4* src4 = (const float4*)(x + (size_t)n0 * IN);
    float4* xs4 = (float4*)xs;
    constexpr int NV = 32 * IN / 4;
#pragma unroll
    for (int idx = t; idx < NV; idx += 256) {
        const int row = idx / (IN / 4);
        xs4[idx] = (n0 + row < N) ? src4[idx] : make_float4(0.f, 0.f, 0.f, 0.f);
    }
    __syncthreads();

    const int idx = t % C;
    const int r0  = t / C;
    constexpr int RSTEP = 256 / C;
    constexpr int RPT   = 32 / RSTEP;
    const int f  = idx / HG;
    const int hd = idx % HG;
    float acc[RPT];
#pragma unroll
    for (int i = 0; i < RPT; ++i) acc[i] = 0.f;
    const float* Wc = W + c0 + hd * F + f;
#pragma unroll 1
    for (int k = 0; k < IN; k += 4) {
        const float w0 = Wc[(k + 0) * OW];
        const float w1 = Wc[(k + 1) * OW];
        const float w2 = Wc[(k + 2) * OW];
        const float w3 = Wc[(k + 3) * OW];
#pragma unroll
        for (int i = 0; i < RPT; ++i) {
            const int r = r0 + i * RSTEP;
            const float4 xv = *(const float4*)&xs[r * IN + k];
            acc[i] = fmaf(xv.x, w0, fmaf(xv.y, w1, fmaf(xv.z, w2, fmaf(xv.w, w3, acc[i]))));
        }
    }
#pragma unroll
    for (int i = 0; i < RPT; ++i) {
        const int r = r0 + i * RSTEP;
        if (n0 + r < N) h[(size_t)(n0 + r) * C + idx] = __float2half(acc[i]);
    }
}

// Attention dots from fp16 h [N, F, HG]; writes a_s/a_d at [n, hb+hl] ([N,8]).
template <int F, int HG>
__global__ __launch_bounds__(256) void k_dots_h(const __half* __restrict__ h,
                                                const float* __restrict__ atts,
                                                const float* __restrict__ attd,
                                                float* __restrict__ as_,
                                                float* __restrict__ ad_, int N, int hb) {
    const int i = blockIdx.x * 256 + threadIdx.x;
    if (i >= N * HG) return;
    const int n  = i / HG;
    const int hl = i % HG;
    const int hg = hb + hl;
    const __half* hp = h + (size_t)n * (F * HG) + hl;
    const float* sv = atts + hg * F;
    const float* dv = attd + hg * F;
    float s = 0.f, d = 0.f;
#pragma unroll
    for (int f = 0; f < F; ++f) {
        const float v = __half2float(hp[f * HG]);
        s = fmaf(v, sv[f], s);
        d = fmaf(v, dv[f], d);
    }
    as_[(size_t)n * 8 + hg] = s;
    ad_[(size_t)n * 8 + hg] = d;
}

// Softmax denominators: thread = (node, head_local). rinv = 1/(sum+eps).
template <int HG>
__global__ __launch_bounds__(256) void k_denom(const int* __restrict__ rowptr,
                                               const int* __restrict__ esrc,
                                               const float* __restrict__ as_,
                                               const float* __restrict__ ad_,
                                               float* __restrict__ rinv, int N, int hb) {
    const int i = blockIdx.x * 256 + threadIdx.x;
    if (i >= N * HG) return;
    const int n  = i / HG;
    const int hl = i % HG;
    const float ad = ad_[(size_t)n * 8 + hb + hl];
    const int r0 = rowptr[n];
    const int r1 = rowptr[n + 1];
    float s = 0.f;
    for (int e = r0; e < r1; ++e)
        s += lrelu_exp(as_[(size_t)esrc[e] * 8 + hb + hl] + ad);
    rinv[(size_t)n * 8 + hb + hl] = 1.f / (s + 1e-16f);
}

// Single-pass aggregation. thread = (node, f).
// MODE 0: outp[n*F+f] += 0.125*a        (fallback, multi-group)
// MODE 1: outp = relu(0.125*a + bias[f]) (layer1 final)
// MODE 2: outp = 0.125*a + bias[f]       (layer2 final -> d_out)
template <int F, int HG, int MODE>
__global__ __launch_bounds__(256) void k_csr_agg(const int* __restrict__ rowptr,
                                                 const int* __restrict__ esrc,
                                                 const float* __restrict__ as_,
                                                 const float* __restrict__ ad_,
                                                 const float* __restrict__ rinv,
                                                 const __half* __restrict__ h,
                                                 const float* __restrict__ bias,
                                                 float* __restrict__ outp,
                                                 int N, int hb) {
    constexpr int NPB = 256 / F;
    const int n = blockIdx.x * NPB + threadIdx.x / F;
    const int f = threadIdx.x % F;
    if (n >= N) return;
    const int r0 = rowptr[n];
    const int r1 = rowptr[n + 1];

    float ad[HG], rv[HG];
#pragma unroll
    for (int k = 0; k < HG; ++k) {
        ad[k] = ad_[(size_t)n * 8 + hb + k];
        rv[k] = rinv[(size_t)n * 8 + hb + k];
    }
    float a0 = 0.f, a1 = 0.f;
    for (int e = r0; e < r1; ++e) {
        const int src = esrc[e];
        const float* sp = as_ + (size_t)src * 8 + hb;
        const __half* hp = h + (size_t)src * (F * HG) + f * HG;
        if constexpr (HG == 8) {
            const float4 s04 = *(const float4*)sp;
            const float4 s44 = *(const float4*)(sp + 4);
            const float4 raw = *(const float4*)hp;
            const __half2* h2 = (const __half2*)&raw;
            float al;
            al = lrelu_exp(s04.x + ad[0]) * rv[0]; a0 = fmaf(al, __low2float(h2[0]),  a0);
            al = lrelu_exp(s04.y + ad[1]) * rv[1]; a1 = fmaf(al, __high2float(h2[0]), a1);
            al = lrelu_exp(s04.z + ad[2]) * rv[2]; a0 = fmaf(al, __low2float(h2[1]),  a0);
            al = lrelu_exp(s04.w + ad[3]) * rv[3]; a1 = fmaf(al, __high2float(h2[1]), a1);
            al = lrelu_exp(s44.x + ad[4]) * rv[4]; a0 = fmaf(al, __low2float(h2[2]),  a0);
            al = lrelu_exp(s44.y + ad[5]) * rv[5]; a1 = fmaf(al, __high2float(h2[2]), a1);
            al = lrelu_exp(s44.z + ad[6]) * rv[6]; a0 = fmaf(al, __low2float(h2[3]),  a0);
            al = lrelu_exp(s44.w + ad[7]) * rv[7]; a1 = fmaf(al, __high2float(h2[3]), a1);
        } else {
#pragma unroll
            for (int k = 0; k < HG; ++k) {
                const float al = lrelu_exp(sp[k] + ad[k]) * rv[k];
                a0 = fmaf(al, __half2float(hp[k]), a0);
            }
        }
    }
    const float a = a0 + a1;
    float* dst = outp + (size_t)n * F + f;
    if constexpr (MODE == 0) {
        *dst += 0.125f * a;
    } else if constexpr (MODE == 1) {
        const float v = 0.125f * a + bias[f];
        *dst = v > 0.f ? v : 0.f;
    } else {
        *dst = 0.125f * a + bias[f];
    }
}

__global__ __launch_bounds__(256) void k_relu_bias(float* __restrict__ a,
                                                   const float* __restrict__ b, int total) {
    const int i = blockIdx.x * 256 + threadIdx.x;
    if (i < total) {
        const float v = a[i] + b[i & 31];
        a[i] = v > 0.f ? v : 0.f;
    }
}

__global__ __launch_bounds__(256) void k_bias_inplace(float* __restrict__ a,
                                                      const float* __restrict__ b, int total) {
    const int i = blockIdx.x * 256 + threadIdx.x;
    if (i < total) a[i] += b[i & 15];
}

template <int HG>
static void run_pipeline(const float* x, const int* ei,
                         const float* W1, const float* as1, const float* ad1, const float* b1,
                         const float* W2, const float* as2, const float* ad2, const float* b2,
                         float* out, int N, int E, char* ws, hipStream_t stream) {
    auto align256 = [](size_t b) { return (b + 255) & ~(size_t)255; };
    size_t off = 0;
    auto alloc = [&](size_t bytes) { char* p = ws + off; off += align256(bytes); return p; };

    __half* hbuf = (__half*)alloc((size_t)N * HG * 32 * 2);   // layer1 [N,32,HG]; layer2 reuses
    float* a_s   = (float*)alloc((size_t)N * 8 * 4);
    float* a_d   = (float*)alloc((size_t)N * 8 * 4);
    float* rinv  = (float*)alloc((size_t)N * 8 * 4);
    float* acc1  = (float*)alloc((size_t)N * 32 * 4);
    int* rowptr  = (int*)alloc((size_t)(N + 1) * 4);
    int* cursor  = (int*)alloc((size_t)N * 4);
    int* deg     = (int*)alloc((size_t)N * 4);
    int* bsum    = (int*)alloc(1024 * 4);
    int* esrc    = (int*)alloc((size_t)E * 4);

    const int NBn = (N + 255) / 256;
    const int NBe = (E + 255) / 256;
    constexpr int G = 8 / HG;

    // ---- CSR build ----
    k_zero_int<<<512, 256, 0, stream>>>(deg, N);
    k_hist<<<NBe, 256, 0, stream>>>(ei, deg, E);
    k_scan_block<<<NBn, 256, 0, stream>>>(deg, rowptr, bsum, N);
    k_scan_sums<<<1, 1024, 0, stream>>>(bsum, NBn);
    k_scan_add<<<NBn, 256, 0, stream>>>(rowptr, bsum, cursor, N, E);
    k_scatter<<<NBe, 256, 0, stream>>>(ei, cursor, esrc, E);

    if (HG < 8) {
        k_zero<<<512, 256, 0, stream>>>(acc1, N * 32);
        k_zero<<<512, 256, 0, stream>>>(out, N * 16);
    }

    constexpr int M1 = (HG == 8) ? 1 : 0;
    constexpr int M2 = (HG == 8) ? 2 : 0;
    const int nbp = (N * HG + 255) / 256;

    // ---- layer 1 ----
    for (int g = 0; g < G; ++g) {
        k_gemm_h<128, HG * 32, 256, 32><<<NBn * 8, 256, 0, stream>>>(x, W1, hbuf, N, g * HG * 32);
        k_dots_h<32, HG><<<nbp, 256, 0, stream>>>(hbuf, as1, ad1, a_s, a_d, N, g * HG);
        k_denom<HG><<<nbp, 256, 0, stream>>>(rowptr, esrc, a_s, a_d, rinv, N, g * HG);
        k_csr_agg<32, HG, M1><<<(N + 7) / 8, 256, 0, stream>>>(rowptr, esrc, a_s, a_d, rinv,
                                                               hbuf, b1, acc1, N, g * HG);
    }
    if (HG < 8) k_relu_bias<<<(N * 32 + 255) / 256, 256, 0, stream>>>(acc1, b1, N * 32);

    // ---- layer 2 ----
    for (int g = 0; g < G; ++g) {
        k_gemm_h<32, HG * 16, 128, 16><<<NBn * 8, 256, 0, stream>>>(acc1, W2, hbuf, N, g * HG * 16);
        k_dots_h<16, HG><<<nbp, 256, 0, stream>>>(hbuf, as2, ad2, a_s, a_d, N, g * HG);
        k_denom<HG><<<nbp, 256, 0, stream>>>(rowptr, esrc, a_s, a_d, rinv, N, g * HG);
        k_csr_agg<16, HG, M2><<<(N + 15) / 16, 256, 0, stream>>>(rowptr, esrc, a_s, a_d, rinv,
                                                                 hbuf, b2, out, N, g * HG);
    }
    if (HG < 8) k_bias_inplace<<<(N * 16 + 255) / 256, 256, 0, stream>>>(out, b2, N * 16);
}

extern "C" void kernel_launch(void* const* d_in, const int* in_sizes, int n_in,
                              void* d_out, int out_size, void* d_ws, size_t ws_size,
                              hipStream_t stream) {
    const float* x   = (const float*)d_in[0];
    const int*   ei  = (const int*)d_in[1];
    const float* W1  = (const float*)d_in[2];
    const float* as1 = (const float*)d_in[3];
    const float* ad1 = (const float*)d_in[4];
    const float* b1  = (const float*)d_in[5];
    const float* W2  = (const float*)d_in[6];
    const float* as2 = (const float*)d_in[7];
    const float* ad2 = (const float*)d_in[8];
    const float* b2  = (const float*)d_in[9];
    float* out = (float*)d_out;

    const int N = in_sizes[0] / 128;
    const int E = in_sizes[1] / 2;

    // bytes for head-group size hg (256B-aligned sections, pad generously):
    auto need = [&](int hg) {
        return (size_t)2 * N * hg * 32 +                 // hbuf fp16
               (size_t)4 * N * (8 + 8 + 8 + 32) +        // a_s, a_d, rinv, acc1
               (size_t)4 * (3 * N + 1 + 1024 + E) +      // ints
               10 * 256;                                 // alignment slop
    };
    char* ws = (char*)d_ws;
    if (ws_size >= need(8)) {
        run_pipeline<8>(x, ei, W1, as1, ad1, b1, W2, as2, ad2, b2, out, N, E, ws, stream);
    } else if (ws_size >= need(4)) {
        run_pipeline<4>(x, ei, W1, as1, ad1, b1, W2, as2, ad2, b2, out, N, E, ws, stream);
    } else if (ws_size >= need(2)) {
        run_pipeline<2>(x, ei, W1, as1, ad1, b1, W2, as2, ad2, b2, out, N, E, ws, stream);
    } else {
        run_pipeline<1>(x, ei, W1, as1, ad1, b1, W2, as2, ad2, b2, out, N, E, ws, stream);
    }
}

// Round 14
// 644.934 us; speedup vs baseline: 8.6243x; 1.0979x over previous
//
#include <hip/hip_runtime.h>
#include <hip/hip_fp16.h>

// ---------------------------------------------------------------------------
// GAT 2-layer forward. CSR owner-computes, materialized per-edge alpha (fp16).
// Layer1: in=128, H=8, F=32.  Layer2: in=32, H=8, F=16.  N=1e5, E=1.6e6.
// r8 profile: k_gemm_h 158us (VALU/LDS-bound), k_csr_agg L1 157us, k_denom
// redundant. This round = r9 minus risk (k_alpha2 serial, no shuffles;
// unroll-capped GEMM; single fallback). r9-r13 were never measured: pod
// timeouts / disk-full — resubmitting unchanged.
// Softmax without max-subtraction (O(1) logits; validated r6-r8).
// ---------------------------------------------------------------------------

__device__ __forceinline__ float lrelu_exp(float v) {
    v = v > 0.f ? v : 0.2f * v;
    return __expf(v);
}

__global__ __launch_bounds__(256) void k_zero(float* __restrict__ p, int n) {
    int i = blockIdx.x * 256 + threadIdx.x;
    const int stride = gridDim.x * 256;
    for (; i < n; i += stride) p[i] = 0.f;
}

__global__ __launch_bounds__(256) void k_zero_int(int* __restrict__ p, int n) {
    int i = blockIdx.x * 256 + threadIdx.x;
    const int stride = gridDim.x * 256;
    for (; i < n; i += stride) p[i] = 0;
}

// ---------------- CSR build (proven r7/r8) ----------------
__global__ __launch_bounds__(256) void k_hist(const int* __restrict__ ei,
                                              int* __restrict__ deg, int E) {
    const int e = blockIdx.x * 256 + threadIdx.x;
    if (e < E) atomicAdd(&deg[ei[E + e]], 1);
}

__global__ __launch_bounds__(256) void k_scan_block(const int* __restrict__ deg,
                                                    int* __restrict__ rowptr,
                                                    int* __restrict__ bsum, int N) {
    __shared__ int s[256];
    const int t = threadIdx.x;
    const int i = blockIdx.x * 256 + t;
    const int v = (i < N) ? deg[i] : 0;
    s[t] = v;
    __syncthreads();
    for (int off = 1; off < 256; off <<= 1) {
        const int tv = (t >= off) ? s[t - off] : 0;
        __syncthreads();
        s[t] += tv;
        __syncthreads();
    }
    if (i < N) rowptr[i] = s[t] - v;
    if (t == 255) bsum[blockIdx.x] = s[255];
}

__global__ __launch_bounds__(1024) void k_scan_sums(int* __restrict__ bsum, int NB) {
    __shared__ int s[1024];
    const int t = threadIdx.x;
    const int v = (t < NB) ? bsum[t] : 0;
    s[t] = v;
    __syncthreads();
    for (int off = 1; off < 1024; off <<= 1) {
        const int tv = (t >= off) ? s[t - off] : 0;
        __syncthreads();
        s[t] += tv;
        __syncthreads();
    }
    if (t < NB) bsum[t] = s[t] - v;
}

__global__ __launch_bounds__(256) void k_scan_add(int* __restrict__ rowptr,
                                                  const int* __restrict__ bsum,
                                                  int* __restrict__ cursor, int N, int E) {
    const int i = blockIdx.x * 256 + threadIdx.x;
    if (i < N) {
        const int r = rowptr[i] + bsum[blockIdx.x];
        rowptr[i] = r;
        cursor[i] = r;
    }
    if (i == 0) rowptr[N] = E;
}

__global__ __launch_bounds__(256) void k_scatter(const int* __restrict__ ei,
                                                 int* __restrict__ cursor,
                                                 int* __restrict__ esrc, int E) {
    const int e = blockIdx.x * 256 + threadIdx.x;
    if (e >= E) return;
    const int src = ei[e];
    const int dst = ei[E + e];
    const int pos = atomicAdd(&cursor[dst], 1);
    esrc[pos] = src;
}

// ---------------- main-path GEMM: 4x8 register tile, W in LDS ----------------
// x[N,IN] @ W[IN,C] -> h fp16 [N, F, 8] (idx = f*8 + head; head=c/F, f=c%F).
// 32 rows/block, 256 threads = 8 row-groups x 32 cols; each thread 4 rows x CJ cols.
template <int IN, int C, int F>
__global__ __launch_bounds__(256) void k_gemm_big(const float* __restrict__ x,
                                                  const float* __restrict__ W,
                                                  __half* __restrict__ h, int N) {
    constexpr int CJ = C / 32;
    constexpr int KC = 32;
    __shared__ float xs[32 * IN];
    __shared__ float wlds[KC * (C + 4)];
    const int t  = threadIdx.x;
    const int n0 = blockIdx.x * 32;

    const float4* src4 = (const float4*)(x + (size_t)n0 * IN);
    float4* xs4 = (float4*)xs;
    constexpr int NV = 32 * IN / 4;
    for (int idx = t; idx < NV; idx += 256) {
        const int row = idx / (IN / 4);
        xs4[idx] = (n0 + row < N) ? src4[idx] : make_float4(0.f, 0.f, 0.f, 0.f);
    }

    const int tc = t & 31;
    const int tr = t >> 5;
    float acc[4][CJ];
#pragma unroll
    for (int i = 0; i < 4; ++i)
#pragma unroll
        for (int j = 0; j < CJ; ++j) acc[i][j] = 0.f;

#pragma unroll 1
    for (int kc = 0; kc < IN; kc += KC) {
        __syncthreads();
        for (int idx = t; idx < KC * C; idx += 256) {
            const int k = idx / C, c = idx % C;
            wlds[k * (C + 4) + c] = W[(size_t)(kc + k) * C + c];
        }
        __syncthreads();
#pragma unroll 1
        for (int q = 0; q < KC / 4; ++q) {
            float4 xv[4];
#pragma unroll
            for (int i = 0; i < 4; ++i)
                xv[i] = *(const float4*)&xs[(tr * 4 + i) * IN + kc + q * 4];
#pragma unroll
            for (int kk = 0; kk < 4; ++kk) {
                float wv[CJ];
#pragma unroll
                for (int j = 0; j < CJ; ++j)
                    wv[j] = wlds[(q * 4 + kk) * (C + 4) + tc + j * 32];
#pragma unroll
                for (int i = 0; i < 4; ++i) {
                    const float xvv = ((const float*)&xv[i])[kk];
#pragma unroll
                    for (int j = 0; j < CJ; ++j)
                        acc[i][j] = fmaf(xvv, wv[j], acc[i][j]);
                }
            }
        }
    }

    if constexpr (C == 256 && F == 32) {
        // c = tc + j*32 -> head=j, f=tc -> idx = tc*8 + j: one 16B store/row
#pragma unroll
        for (int i = 0; i < 4; ++i) {
            const int r = n0 + tr * 4 + i;
            if (r < N) {
                __half tmp[8];
#pragma unroll
                for (int j = 0; j < 8; ++j) tmp[j] = __float2half(acc[i][j]);
                *(float4*)(h + (size_t)r * 256 + tc * 8) = *(const float4*)tmp;
            }
        }
    } else {
#pragma unroll
        for (int i = 0; i < 4; ++i) {
            const int r = n0 + tr * 4 + i;
            if (r < N) {
#pragma unroll
                for (int j = 0; j < CJ; ++j) {
                    const int c = tc + j * 32;
                    h[(size_t)r * C + (c % F) * 8 + (c / F)] = __float2half(acc[i][j]);
                }
            }
        }
    }
}

// Attention dots from fp16 h [N, F, HG]; writes a_s/a_d [N,8] at head hb+hl.
template <int F, int HG>
__global__ __launch_bounds__(256) void k_dots_h(const __half* __restrict__ h,
                                                const float* __restrict__ atts,
                                                const float* __restrict__ attd,
                                                float* __restrict__ as_,
                                                float* __restrict__ ad_, int N, int hb) {
    const int i = blockIdx.x * 256 + threadIdx.x;
    if (i >= N * HG) return;
    const int n  = i / HG;
    const int hl = i % HG;
    const int hg = hb + hl;
    const __half* hp = h + (size_t)n * (F * HG) + hl;
    const float* sv = atts + hg * F;
    const float* dv = attd + hg * F;
    float s = 0.f, d = 0.f;
#pragma unroll
    for (int f = 0; f < F; ++f) {
        const float v = __half2float(hp[f * HG]);
        s = fmaf(v, sv[f], s);
        d = fmaf(v, dv[f], d);
    }
    as_[(size_t)n * 8 + hg] = s;
    ad_[(size_t)n * 8 + hg] = d;
}

// Per-edge alpha, serial per (node,head) -- no cross-lane ops.
// exp computed once per (edge,head); fp16 ex stored in CSR order; denominator
// summed from the same fp16-rounded values (num/den consistent).
__global__ __launch_bounds__(256) void k_alpha2(const int* __restrict__ rowptr,
                                                const int* __restrict__ esrc,
                                                const float* __restrict__ as_,
                                                const float* __restrict__ ad_,
                                                __half* __restrict__ exbuf,
                                                float* __restrict__ rinv, int N) {
    const int i = blockIdx.x * 256 + threadIdx.x;
    if (i >= N * 8) return;
    const int n  = i >> 3;
    const int hh = i & 7;
    const float adv = ad_[i];
    const int r0 = rowptr[n], r1 = rowptr[n + 1];
    float den = 0.f;
    for (int e = r0; e < r1; ++e) {
        const float ex = lrelu_exp(as_[(size_t)esrc[e] * 8 + hh] + adv);
        const __half hx = __float2half(ex);
        exbuf[(size_t)e * 8 + hh] = hx;
        den += __half2float(hx);
    }
    rinv[i] = 1.f / (den + 1e-16f);
}

// Single-pass aggregation with materialized ex. thread=(node,f).
// MODE 1: out = relu(0.125*s + bias)   MODE 2: out = 0.125*s + bias
template <int F, int MODE>
__global__ __launch_bounds__(256) void k_agg_ex(const int* __restrict__ rowptr,
                                                const int* __restrict__ esrc,
                                                const __half* __restrict__ exbuf,
                                                const float* __restrict__ rinv,
                                                const __half* __restrict__ h,
                                                const float* __restrict__ bias,
                                                float* __restrict__ outp, int N) {
    constexpr int NPB = 256 / F;
    const int n = blockIdx.x * NPB + threadIdx.x / F;
    const int f = threadIdx.x % F;
    if (n >= N) return;
    const int r0 = rowptr[n], r1 = rowptr[n + 1];

    float acc[8];
#pragma unroll
    for (int k = 0; k < 8; ++k) acc[k] = 0.f;

    for (int e = r0; e < r1; ++e) {
        const int src = esrc[e];
        const float4 exr = *(const float4*)(exbuf + (size_t)e * 8);
        const float4 raw = *(const float4*)(h + (size_t)src * (F * 8) + f * 8);
        const __half2* e2 = (const __half2*)&exr;
        const __half2* h2 = (const __half2*)&raw;
#pragma unroll
        for (int k = 0; k < 4; ++k) {
            const float2 ef = __half22float2(e2[k]);
            const float2 hf = __half22float2(h2[k]);
            acc[2 * k]     = fmaf(ef.x, hf.x, acc[2 * k]);
            acc[2 * k + 1] = fmaf(ef.y, hf.y, acc[2 * k + 1]);
        }
    }
    const float* rv = rinv + (size_t)n * 8;
    float s = 0.f;
#pragma unroll
    for (int k = 0; k < 8; ++k) s += rv[k] * acc[k];
    float v = 0.125f * s + bias[f];
    if constexpr (MODE == 1) v = v > 0.f ? v : 0.f;
    outp[(size_t)n * F + f] = v;
}

// ---------------- fallback path (r8-proven, single HG=4 instantiation) -------
template <int IN, int C, int OW, int F>
__global__ __launch_bounds__(256) void k_gemm_h(const float* __restrict__ x,
                                                const float* __restrict__ W,
                                                __half* __restrict__ h, int N, int c0) {
    constexpr int HG = C / F;
    __shared__ float xs[32 * IN];
    const int t  = threadIdx.x;
    const int n0 = blockIdx.x * 32;
    const float4* src4 = (const float4*)(x + (size_t)n0 * IN);
    float4* xs4 = (float4*)xs;
    constexpr int NV = 32 * IN / 4;
    for (int idx = t; idx < NV; idx += 256) {
        const int row = idx / (IN / 4);
        xs4[idx] = (n0 + row < N) ? src4[idx] : make_float4(0.f, 0.f, 0.f, 0.f);
    }
    __syncthreads();
    const int idx = t % C;
    const int r0  = t / C;
    constexpr int RSTEP = 256 / C;
    constexpr int RPT   = 32 / RSTEP;
    const int f  = idx / HG;
    const int hd = idx % HG;
    float acc[RPT];
#pragma unroll
    for (int i = 0; i < RPT; ++i) acc[i] = 0.f;
    const float* Wc = W + c0 + hd * F + f;
#pragma unroll 1
    for (int k = 0; k < IN; k += 4) {
        const float w0 = Wc[(k + 0) * OW];
        const float w1 = Wc[(k + 1) * OW];
        const float w2 = Wc[(k + 2) * OW];
        const float w3 = Wc[(k + 3) * OW];
#pragma unroll
        for (int i = 0; i < RPT; ++i) {
            const int r = r0 + i * RSTEP;
            const float4 xv = *(const float4*)&xs[r * IN + k];
            acc[i] = fmaf(xv.x, w0, fmaf(xv.y, w1, fmaf(xv.z, w2, fmaf(xv.w, w3, acc[i]))));
        }
    }
#pragma unroll
    for (int i = 0; i < RPT; ++i) {
        const int r = r0 + i * RSTEP;
        if (n0 + r < N) h[(size_t)(n0 + r) * C + idx] = __float2half(acc[i]);
    }
}

template <int HG>
__global__ __launch_bounds__(256) void k_denom(const int* __restrict__ rowptr,
                                               const int* __restrict__ esrc,
                                               const float* __restrict__ as_,
                                               const float* __restrict__ ad_,
                                               float* __restrict__ rinv, int N, int hb) {
    const int i = blockIdx.x * 256 + threadIdx.x;
    if (i >= N * HG) return;
    const int n  = i / HG;
    const int hl = i % HG;
    const float ad = ad_[(size_t)n * 8 + hb + hl];
    const int r0 = rowptr[n];
    const int r1 = rowptr[n + 1];
    float s = 0.f;
    for (int e = r0; e < r1; ++e)
        s += lrelu_exp(as_[(size_t)esrc[e] * 8 + hb + hl] + ad);
    rinv[(size_t)n * 8 + hb + hl] = 1.f / (s + 1e-16f);
}

template <int F, int HG>
__global__ __launch_bounds__(256) void k_csr_agg_hg(const int* __restrict__ rowptr,
                                                    const int* __restrict__ esrc,
                                                    const float* __restrict__ as_,
                                                    const float* __restrict__ ad_,
                                                    const float* __restrict__ rinv,
                                                    const __half* __restrict__ h,
                                                    float* __restrict__ outp,
                                                    int N, int hb) {
    constexpr int NPB = 256 / F;
    const int n = blockIdx.x * NPB + threadIdx.x / F;
    const int f = threadIdx.x % F;
    if (n >= N) return;
    const int r0 = rowptr[n];
    const int r1 = rowptr[n + 1];
    float ad[HG], rv[HG];
#pragma unroll
    for (int k = 0; k < HG; ++k) {
        ad[k] = ad_[(size_t)n * 8 + hb + k];
        rv[k] = rinv[(size_t)n * 8 + hb + k];
    }
    float a0 = 0.f;
    for (int e = r0; e < r1; ++e) {
        const int src = esrc[e];
        const float* sp = as_ + (size_t)src * 8 + hb;
        const __half* hp = h + (size_t)src * (F * HG) + f * HG;
#pragma unroll
        for (int k = 0; k < HG; ++k) {
            const float al = lrelu_exp(sp[k] + ad[k]) * rv[k];
            a0 = fmaf(al, __half2float(hp[k]), a0);
        }
    }
    outp[(size_t)n * F + f] += 0.125f * a0;
}

__global__ __launch_bounds__(256) void k_relu_bias(float* __restrict__ a,
                                                   const float* __restrict__ b, int total) {
    const int i = blockIdx.x * 256 + threadIdx.x;
    if (i < total) {
        const float v = a[i] + b[i & 31];
        a[i] = v > 0.f ? v : 0.f;
    }
}

__global__ __launch_bounds__(256) void k_bias_inplace(float* __restrict__ a,
                                                      const float* __restrict__ b, int total) {
    const int i = blockIdx.x * 256 + threadIdx.x;
    if (i < total) a[i] += b[i & 15];
}

// ---------------- drivers ----------------
static void csr_build(const int* ei, int* deg, int* rowptr, int* bsum, int* cursor,
                      int* esrc, int N, int E, hipStream_t stream) {
    const int NBn = (N + 255) / 256;
    const int NBe = (E + 255) / 256;
    k_zero_int<<<512, 256, 0, stream>>>(deg, N);
    k_hist<<<NBe, 256, 0, stream>>>(ei, deg, E);
    k_scan_block<<<NBn, 256, 0, stream>>>(deg, rowptr, bsum, N);
    k_scan_sums<<<1, 1024, 0, stream>>>(bsum, NBn);
    k_scan_add<<<NBn, 256, 0, stream>>>(rowptr, bsum, cursor, N, E);
    k_scatter<<<NBe, 256, 0, stream>>>(ei, cursor, esrc, E);
}

static void run_full(const float* x, const int* ei,
                     const float* W1, const float* as1, const float* ad1, const float* b1,
                     const float* W2, const float* as2, const float* ad2, const float* b2,
                     float* out, int N, int E, char* ws, hipStream_t stream) {
    auto align256 = [](size_t b) { return (b + 255) & ~(size_t)255; };
    size_t off = 0;
    auto alloc = [&](size_t bytes) { char* p = ws + off; off += align256(bytes); return p; };

    __half* hbuf  = (__half*)alloc((size_t)N * 256 * 2);
    __half* exbuf = (__half*)alloc((size_t)E * 8 * 2);
    float* a_s    = (float*)alloc((size_t)N * 8 * 4);
    float* a_d    = (float*)alloc((size_t)N * 8 * 4);
    float* rinv   = (float*)alloc((size_t)N * 8 * 4);
    float* acc1   = (float*)alloc((size_t)N * 32 * 4);
    int* rowptr   = (int*)alloc((size_t)(N + 1) * 4);
    int* cursor   = (int*)alloc((size_t)N * 4);
    int* deg      = (int*)alloc((size_t)N * 4);
    int* bsum     = (int*)alloc(1024 * 4);
    int* esrc     = (int*)alloc((size_t)E * 4);

    csr_build(ei, deg, rowptr, bsum, cursor, esrc, N, E, stream);

    const int NBg = (N + 31) / 32;
    const int nbp = (N * 8 + 255) / 256;
    // layer 1
    k_gemm_big<128, 256, 32><<<NBg, 256, 0, stream>>>(x, W1, hbuf, N);
    k_dots_h<32, 8><<<nbp, 256, 0, stream>>>(hbuf, as1, ad1, a_s, a_d, N, 0);
    k_alpha2<<<nbp, 256, 0, stream>>>(rowptr, esrc, a_s, a_d, exbuf, rinv, N);
    k_agg_ex<32, 1><<<(N + 7) / 8, 256, 0, stream>>>(rowptr, esrc, exbuf, rinv, hbuf, b1, acc1, N);
    // layer 2
    k_gemm_big<32, 128, 16><<<NBg, 256, 0, stream>>>(acc1, W2, hbuf, N);
    k_dots_h<16, 8><<<nbp, 256, 0, stream>>>(hbuf, as2, ad2, a_s, a_d, N, 0);
    k_alpha2<<<nbp, 256, 0, stream>>>(rowptr, esrc, a_s, a_d, exbuf, rinv, N);
    k_agg_ex<16, 2><<<(N + 15) / 16, 256, 0, stream>>>(rowptr, esrc, exbuf, rinv, hbuf, b2, out, N);
}

static void run_fallback4(const float* x, const int* ei,
                          const float* W1, const float* as1, const float* ad1, const float* b1,
                          const float* W2, const float* as2, const float* ad2, const float* b2,
                          float* out, int N, int E, char* ws, hipStream_t stream) {
    constexpr int HG = 4;
    auto align256 = [](size_t b) { return (b + 255) & ~(size_t)255; };
    size_t off = 0;
    auto alloc = [&](size_t bytes) { char* p = ws + off; off += align256(bytes); return p; };

    __half* hbuf = (__half*)alloc((size_t)N * HG * 32 * 2);
    float* a_s   = (float*)alloc((size_t)N * 8 * 4);
    float* a_d   = (float*)alloc((size_t)N * 8 * 4);
    float* rinv  = (float*)alloc((size_t)N * 8 * 4);
    float* acc1  = (float*)alloc((size_t)N * 32 * 4);
    int* rowptr  = (int*)alloc((size_t)(N + 1) * 4);
    int* cursor  = (int*)alloc((size_t)N * 4);
    int* deg     = (int*)alloc((size_t)N * 4);
    int* bsum    = (int*)alloc(1024 * 4);
    int* esrc    = (int*)alloc((size_t)E * 4);

    csr_build(ei, deg, rowptr, bsum, cursor, esrc, N, E, stream);

    k_zero<<<512, 256, 0, stream>>>(acc1, N * 32);
    k_zero<<<512, 256, 0, stream>>>(out, N * 16);

    const int NBn = (N + 255) / 256;
    const int nbp = (N * HG + 255) / 256;

    for (int g = 0; g < 2; ++g) {
        k_gemm_h<128, 128, 256, 32><<<NBn * 8, 256, 0, stream>>>(x, W1, hbuf, N, g * 128);
        k_dots_h<32, HG><<<nbp, 256, 0, stream>>>(hbuf, as1, ad1, a_s, a_d, N, g * HG);
        k_denom<HG><<<nbp, 256, 0, stream>>>(rowptr, esrc, a_s, a_d, rinv, N, g * HG);
        k_csr_agg_hg<32, HG><<<(N + 7) / 8, 256, 0, stream>>>(rowptr, esrc, a_s, a_d, rinv,
                                                              hbuf, acc1, N, g * HG);
    }
    k_relu_bias<<<(N * 32 + 255) / 256, 256, 0, stream>>>(acc1, b1, N * 32);

    for (int g = 0; g < 2; ++g) {
        k_gemm_h<32, 64, 128, 16><<<NBn * 8, 256, 0, stream>>>(acc1, W2, hbuf, N, g * 64);
        k_dots_h<16, HG><<<nbp, 256, 0, stream>>>(hbuf, as2, ad2, a_s, a_d, N, g * HG);
        k_denom<HG><<<nbp, 256, 0, stream>>>(rowptr, esrc, a_s, a_d, rinv, N, g * HG);
        k_csr_agg_hg<16, HG><<<(N + 15) / 16, 256, 0, stream>>>(rowptr, esrc, a_s, a_d, rinv,
                                                                hbuf, out, N, g * HG);
    }
    k_bias_inplace<<<(N * 16 + 255) / 256, 256, 0, stream>>>(out, b2, N * 16);
}

extern "C" void kernel_launch(void* const* d_in, const int* in_sizes, int n_in,
                              void* d_out, int out_size, void* d_ws, size_t ws_size,
                              hipStream_t stream) {
    const float* x   = (const float*)d_in[0];
    const int*   ei  = (const int*)d_in[1];
    const float* W1  = (const float*)d_in[2];
    const float* as1 = (const float*)d_in[3];
    const float* ad1 = (const float*)d_in[4];
    const float* b1  = (const float*)d_in[5];
    const float* W2  = (const float*)d_in[6];
    const float* as2 = (const float*)d_in[7];
    const float* ad2 = (const float*)d_in[8];
    const float* b2  = (const float*)d_in[9];
    float* out = (float*)d_out;

    const int N = in_sizes[0] / 128;
    const int E = in_sizes[1] / 2;

    const size_t need_full = (size_t)2 * N * 256 + (size_t)2 * E * 8 +
                             (size_t)4 * N * (8 + 8 + 8 + 32) +
                             (size_t)4 * (3 * N + 1 + 1024 + E) + 16 * 256;
    char* ws = (char*)d_ws;
    if (ws_size >= need_full) {
        run_full(x, ei, W1, as1, ad1, b1, W2, as2, ad2, b2, out, N, E, ws, stream);
    } else {
        run_fallback4(x, ei, W1, as1, ad1, b1, W2, as2, ad2, b2, out, N, E, ws, stream);
    }
}